// Round 4
// baseline (217.502 us; speedup 1.0000x reference)
//
#include <hip/hip_runtime.h>

// Skeleton FK: angles [B,16,6] f32, xyz [1,16,3] f32 -> out [B,16,3] f32.
// R4: kill address divergence. Wave-local LDS transpose: coalesced global<->LDS,
// per-lane compute reads own element from LDS. 4 passes of 4 joints; chain state
// (current + saved joint-3) in registers. LDS element stride = 7 float4 (pad) so
// all b128 LDS ops spread uniformly over the 8 bank groups (conflict-free).

namespace {

constexpr int NJ = 16;

__device__ __forceinline__ void rot6d(const float* __restrict__ a, float R[9]) {
    float inv1 = rsqrtf(a[0]*a[0] + a[1]*a[1] + a[2]*a[2]);
    float b10 = a[0]*inv1, b11 = a[1]*inv1, b12 = a[2]*inv1;
    float d = b10*a[3] + b11*a[4] + b12*a[5];
    float c0 = a[3] - d*b10, c1 = a[4] - d*b11, c2 = a[5] - d*b12;
    float inv2 = rsqrtf(c0*c0 + c1*c1 + c2*c2);
    float b20 = c0*inv2, b21 = c1*inv2, b22 = c2*inv2;
    R[0] = b10; R[1] = b11; R[2] = b12;
    R[3] = b20; R[4] = b21; R[5] = b22;
    R[6] = b11*b22 - b12*b21;
    R[7] = b12*b20 - b10*b22;
    R[8] = b10*b21 - b11*b20;
}

// One tree edge: given child local rot R and t = ref[c]-ref[p], advance (Rw,pw).
__device__ __forceinline__ void chain_step(const float R[9],
                                           float tx, float ty, float tz,
                                           float Rw[9], float pw[3]) {
    float lt0 = R[0]*tx + R[1]*ty + R[2]*tz;
    float lt1 = R[3]*tx + R[4]*ty + R[5]*tz;
    float lt2 = R[6]*tx + R[7]*ty + R[8]*tz;
    float np0 = Rw[0]*lt0 + Rw[1]*lt1 + Rw[2]*lt2 + pw[0];
    float np1 = Rw[3]*lt0 + Rw[4]*lt1 + Rw[5]*lt2 + pw[1];
    float np2 = Rw[6]*lt0 + Rw[7]*lt1 + Rw[8]*lt2 + pw[2];
    float T[9];
#pragma unroll
    for (int i = 0; i < 3; ++i)
#pragma unroll
        for (int j = 0; j < 3; ++j)
            T[i*3 + j] = Rw[i*3 + 0]*R[0*3 + j]
                       + Rw[i*3 + 1]*R[1*3 + j]
                       + Rw[i*3 + 2]*R[2*3 + j];
#pragma unroll
    for (int k = 0; k < 9; ++k) Rw[k] = T[k];
    pw[0] = np0; pw[1] = np1; pw[2] = np2;
}

__global__ __launch_bounds__(256, 4) void skel_kernel(
    const float* __restrict__ angles,
    const float* __restrict__ xyz,
    float* __restrict__ out,
    int batch)
{
    // 4 waves * 64 elements * 7 float4 (6 used + 1 pad) = 28672 B
    __shared__ float4 lds[4 * 64 * 7];

    const int tid  = threadIdx.x;
    const int wave = tid >> 6;
    const int lane = tid & 63;
    float4* W = &lds[wave * (64 * 7)];

    const int waveElem = blockIdx.x * 256 + wave * 64;   // base element of this wave
    const int myElem   = waveElem + lane;
    const bool meOk    = (myElem < batch);

    const float4* ang4 = (const float4*)angles;          // elem*24 + chunk
    float4*       out4 = (float4*)out;                   // elem*12 + chunk

    // ---- coalesced load of pass p's 6 chunks/element into LDS ----
    auto load_pass = [&](int p) {
#pragma unroll
        for (int j = 0; j < 6; ++j) {
            int flat = 64 * j + lane;
            int le = flat / 6;           // element within wave
            int lc = flat - 6 * le;      // chunk within pass
            int ge = waveElem + le;
            float4 v = make_float4(0.f, 0.f, 0.f, 0.f);
            if (ge < batch) v = ang4[(size_t)ge * 24 + p * 6 + lc];
            W[le * 7 + lc] = v;
        }
    };

    // ---- read my element's 24 floats from LDS ----
    auto read_mine = [&](float* a) {
#pragma unroll
        for (int c = 0; c < 6; ++c) {
            float4 v = W[lane * 7 + c];
            a[4*c + 0] = v.x; a[4*c + 1] = v.y; a[4*c + 2] = v.z; a[4*c + 3] = v.w;
        }
    };

    // ---- stage 12 outputs in LDS, then coalesced store ----
    auto store_pass = [&](int p, const float* o) {
        W[lane * 7 + 0] = make_float4(o[0], o[1], o[2],  o[3]);
        W[lane * 7 + 1] = make_float4(o[4], o[5], o[6],  o[7]);
        W[lane * 7 + 2] = make_float4(o[8], o[9], o[10], o[11]);
        __syncthreads();
#pragma unroll
        for (int j = 0; j < 3; ++j) {
            int flat = 64 * j + lane;
            int le = flat / 3;
            int lc = flat - 3 * le;
            int ge = waveElem + le;
            if (ge < batch) out4[(size_t)ge * 12 + p * 3 + lc] = W[le * 7 + lc];
        }
    };

    auto tvec = [&](int c, int p, float& tx, float& ty, float& tz) {
        tx = xyz[c*3 + 0] - xyz[p*3 + 0];
        ty = xyz[c*3 + 1] - xyz[p*3 + 1];
        tz = xyz[c*3 + 2] - xyz[p*3 + 2];
    };

    float Rw[9], pw[3], Rw3[9], pw3[3];
    float a[24], R[9], o[12];
    float tx, ty, tz;

    // ================= pass 0: joints 0,1,2,3 =================
    load_pass(0);
    __syncthreads();
    read_mine(a);

    rot6d(&a[0], Rw);
    {
        float x = xyz[0], y = xyz[1], z = xyz[2];
        pw[0] = Rw[0]*x + Rw[1]*y + Rw[2]*z;
        pw[1] = Rw[3]*x + Rw[4]*y + Rw[5]*z;
        pw[2] = Rw[6]*x + Rw[7]*y + Rw[8]*z;
    }
    o[0] = pw[0]; o[1] = pw[1]; o[2] = pw[2];

    rot6d(&a[6], R);  tvec(1, 0, tx, ty, tz); chain_step(R, tx, ty, tz, Rw, pw);
    o[3] = pw[0]; o[4] = pw[1]; o[5] = pw[2];
    rot6d(&a[12], R); tvec(2, 1, tx, ty, tz); chain_step(R, tx, ty, tz, Rw, pw);
    o[6] = pw[0]; o[7] = pw[1]; o[8] = pw[2];
    rot6d(&a[18], R); tvec(3, 2, tx, ty, tz); chain_step(R, tx, ty, tz, Rw, pw);
    o[9] = pw[0]; o[10] = pw[1]; o[11] = pw[2];

#pragma unroll
    for (int k = 0; k < 9; ++k) Rw3[k] = Rw[k];
    pw3[0] = pw[0]; pw3[1] = pw[1]; pw3[2] = pw[2];

    store_pass(0, o);
    __syncthreads();

    // ================= pass 1: joints 4,5,6,7 =================
    // edges: 3-4, 4-5, 3-6, 6-7   (current state entering = joint 3)
    load_pass(1);
    __syncthreads();
    read_mine(a);

    rot6d(&a[0], R);  tvec(4, 3, tx, ty, tz); chain_step(R, tx, ty, tz, Rw, pw);
    o[0] = pw[0]; o[1] = pw[1]; o[2] = pw[2];
    rot6d(&a[6], R);  tvec(5, 4, tx, ty, tz); chain_step(R, tx, ty, tz, Rw, pw);
    o[3] = pw[0]; o[4] = pw[1]; o[5] = pw[2];

#pragma unroll
    for (int k = 0; k < 9; ++k) Rw[k] = Rw3[k];          // restore joint-3 state
    pw[0] = pw3[0]; pw[1] = pw3[1]; pw[2] = pw3[2];

    rot6d(&a[12], R); tvec(6, 3, tx, ty, tz); chain_step(R, tx, ty, tz, Rw, pw);
    o[6] = pw[0]; o[7] = pw[1]; o[8] = pw[2];
    rot6d(&a[18], R); tvec(7, 6, tx, ty, tz); chain_step(R, tx, ty, tz, Rw, pw);
    o[9] = pw[0]; o[10] = pw[1]; o[11] = pw[2];
    // current state = joint 7 (needed for pass 2)

    store_pass(1, o);
    __syncthreads();

    // ================= pass 2: joints 8,9,10,11 =================
    // edges: 7-8, 8-9, 9-10, 3-11
    load_pass(2);
    __syncthreads();
    read_mine(a);

    rot6d(&a[0], R);  tvec(8, 7, tx, ty, tz); chain_step(R, tx, ty, tz, Rw, pw);
    o[0] = pw[0]; o[1] = pw[1]; o[2] = pw[2];
    rot6d(&a[6], R);  tvec(9, 8, tx, ty, tz); chain_step(R, tx, ty, tz, Rw, pw);
    o[3] = pw[0]; o[4] = pw[1]; o[5] = pw[2];
    rot6d(&a[12], R); tvec(10, 9, tx, ty, tz); chain_step(R, tx, ty, tz, Rw, pw);
    o[6] = pw[0]; o[7] = pw[1]; o[8] = pw[2];

#pragma unroll
    for (int k = 0; k < 9; ++k) Rw[k] = Rw3[k];          // restore joint-3 state
    pw[0] = pw3[0]; pw[1] = pw3[1]; pw[2] = pw3[2];

    rot6d(&a[18], R); tvec(11, 3, tx, ty, tz); chain_step(R, tx, ty, tz, Rw, pw);
    o[9] = pw[0]; o[10] = pw[1]; o[11] = pw[2];
    // current state = joint 11

    store_pass(2, o);
    __syncthreads();

    // ================= pass 3: joints 12,13,14,15 =================
    // edges: 11-12, 12-13, 13-14, 14-15
    load_pass(3);
    __syncthreads();
    read_mine(a);

    rot6d(&a[0], R);  tvec(12, 11, tx, ty, tz); chain_step(R, tx, ty, tz, Rw, pw);
    o[0] = pw[0]; o[1] = pw[1]; o[2] = pw[2];
    rot6d(&a[6], R);  tvec(13, 12, tx, ty, tz); chain_step(R, tx, ty, tz, Rw, pw);
    o[3] = pw[0]; o[4] = pw[1]; o[5] = pw[2];
    rot6d(&a[12], R); tvec(14, 13, tx, ty, tz); chain_step(R, tx, ty, tz, Rw, pw);
    o[6] = pw[0]; o[7] = pw[1]; o[8] = pw[2];
    rot6d(&a[18], R); tvec(15, 14, tx, ty, tz); chain_step(R, tx, ty, tz, Rw, pw);
    o[9] = pw[0]; o[10] = pw[1]; o[11] = pw[2];

    store_pass(3, o);
    (void)meOk;
}

} // namespace

extern "C" void kernel_launch(void* const* d_in, const int* in_sizes, int n_in,
                              void* d_out, int out_size, void* d_ws, size_t ws_size,
                              hipStream_t stream) {
    const float* angles = (const float*)d_in[0];   // [B, 16, 6] f32
    const float* xyz    = (const float*)d_in[1];   // [1, 16, 3] f32
    float* out          = (float*)d_out;           // [B, 16, 3] f32

    const int batch = in_sizes[0] / (NJ * 6);
    dim3 grid((batch + 255) / 256);
    skel_kernel<<<grid, 256, 0, stream>>>(angles, xyz, out, batch);
}

// Round 5
// 199.540 us; speedup vs baseline: 1.0900x; 1.0900x over previous
//
#include <hip/hip_runtime.h>

// Skeleton FK: angles [B,16,6] f32, xyz [1,16,3] f32 -> out [B,16,3] f32.
// R5: single-wave blocks (64 thr). Two 192-B aligned halves per element (joints 0-7,
// 8-15). Coalesced global float4 loads -> padded LDS slots (13 float4/elem) ->
// per-lane compute from own slot -> outputs overlaid in-place into dead input dwords
// -> coalesced float4 stores. Half-B prefetched into registers before half-A compute
// (sched_barrier pins it; R2/R3 lesson: scheduler sinks loads otherwise). Independent
// 1-wave blocks (12/CU by LDS) pipeline without block-wide barrier stalls (R4 lesson).

namespace {

constexpr int NJ = 16;
constexpr int SLOT = 13;   // float4 per element slot: 12 data + 1 pad (bank spread)

__device__ __forceinline__ void rot6d(const float a[6], float R[9]) {
    float inv1 = rsqrtf(a[0]*a[0] + a[1]*a[1] + a[2]*a[2]);
    float b10 = a[0]*inv1, b11 = a[1]*inv1, b12 = a[2]*inv1;
    float d = b10*a[3] + b11*a[4] + b12*a[5];
    float c0 = a[3] - d*b10, c1 = a[4] - d*b11, c2 = a[5] - d*b12;
    float inv2 = rsqrtf(c0*c0 + c1*c1 + c2*c2);
    float b20 = c0*inv2, b21 = c1*inv2, b22 = c2*inv2;
    R[0] = b10; R[1] = b11; R[2] = b12;
    R[3] = b20; R[4] = b21; R[5] = b22;
    R[6] = b11*b22 - b12*b21;
    R[7] = b12*b20 - b10*b22;
    R[8] = b10*b21 - b11*b20;
}

__device__ __forceinline__ void chain_step(const float R[9],
                                           float tx, float ty, float tz,
                                           float Rw[9], float pw[3]) {
    float lt0 = R[0]*tx + R[1]*ty + R[2]*tz;
    float lt1 = R[3]*tx + R[4]*ty + R[5]*tz;
    float lt2 = R[6]*tx + R[7]*ty + R[8]*tz;
    float np0 = Rw[0]*lt0 + Rw[1]*lt1 + Rw[2]*lt2 + pw[0];
    float np1 = Rw[3]*lt0 + Rw[4]*lt1 + Rw[5]*lt2 + pw[1];
    float np2 = Rw[6]*lt0 + Rw[7]*lt1 + Rw[8]*lt2 + pw[2];
    float T[9];
#pragma unroll
    for (int i = 0; i < 3; ++i)
#pragma unroll
        for (int j = 0; j < 3; ++j)
            T[i*3 + j] = Rw[i*3 + 0]*R[0*3 + j]
                       + Rw[i*3 + 1]*R[1*3 + j]
                       + Rw[i*3 + 2]*R[2*3 + j];
#pragma unroll
    for (int k = 0; k < 9; ++k) Rw[k] = T[k];
    pw[0] = np0; pw[1] = np1; pw[2] = np2;
}

__global__ __launch_bounds__(64) void skel_kernel(
    const float* __restrict__ angles,
    const float* __restrict__ xyz,
    float* __restrict__ out,
    int batch)
{
    __shared__ float4 W[64 * SLOT];   // 13312 B -> 12 blocks/CU

    const int lane      = threadIdx.x;       // block = exactly one wave
    const int blockElem = blockIdx.x * 64;
    const int clampHi   = batch - 1;

    const float4* ang4 = (const float4*)angles;   // elem*24 + chunk
    float4*       out4 = (float4*)out;            // elem*12 + chunk

    // ---- half-A loads (chunks 0..11 of each element), fully coalesced ----
    float4 vA[12];
#pragma unroll
    for (int j = 0; j < 12; ++j) {
        int flat = 64 * j + lane;
        int le = flat / 12, lc = flat % 12;
        int ge = min(blockElem + le, clampHi);    // clamp: branchless OOB safety
        vA[j] = ang4[(size_t)ge * 24 + lc];
    }
#pragma unroll
    for (int j = 0; j < 12; ++j) {
        int flat = 64 * j + lane;
        int le = flat / 12, lc = flat % 12;
        W[le * SLOT + lc] = vA[j];
    }

    // ---- half-B prefetch (chunks 12..23) into registers, hidden under compute-A ----
    float4 vB[12];
#pragma unroll
    for (int j = 0; j < 12; ++j) {
        int flat = 64 * j + lane;
        int le = flat / 12, lc = flat % 12;
        int ge = min(blockElem + le, clampHi);
        vB[j] = ang4[(size_t)ge * 24 + 12 + lc];
    }
    __builtin_amdgcn_sched_barrier(0);   // forbid sinking the prefetch into compute
    __syncthreads();

    float*  slot  = (float*)&W[lane * SLOT];
    float2* slot2 = (float2*)slot;

    float Rw[9], pw[3], Rw3[9], pw3[3], R[9], a[6];

    auto read6 = [&](int jj, float* aa) {   // input floats 6jj..6jj+5 of my slot
        float2 x = slot2[3*jj + 0], y = slot2[3*jj + 1], z = slot2[3*jj + 2];
        aa[0] = x.x; aa[1] = x.y; aa[2] = y.x; aa[3] = y.y; aa[4] = z.x; aa[5] = z.y;
    };
    auto write3 = [&](int jj) {             // output floats 3jj..3jj+2 (in-place, safe)
        slot[3*jj + 0] = pw[0]; slot[3*jj + 1] = pw[1]; slot[3*jj + 2] = pw[2];
    };
    auto tvec = [&](int c, int p, float& tx, float& ty, float& tz) {
        tx = xyz[c*3 + 0] - xyz[p*3 + 0];
        ty = xyz[c*3 + 1] - xyz[p*3 + 1];
        tz = xyz[c*3 + 2] - xyz[p*3 + 2];
    };

    // ================= half A: joints 0..7 =================
    read6(0, a);
    rot6d(a, Rw);
    {
        float x = xyz[0], y = xyz[1], z = xyz[2];
        pw[0] = Rw[0]*x + Rw[1]*y + Rw[2]*z;
        pw[1] = Rw[3]*x + Rw[4]*y + Rw[5]*z;
        pw[2] = Rw[6]*x + Rw[7]*y + Rw[8]*z;
    }
    write3(0);

    constexpr int PA[7] = {0, 1, 2, 3, 4, 3, 6};   // parents of children 1..7
#pragma unroll
    for (int e = 0; e < 7; ++e) {
        const int c = e + 1, p = PA[e];
        if (p == 3) {   // restore branch state (no-op copy for c==4)
#pragma unroll
            for (int k = 0; k < 9; ++k) Rw[k] = Rw3[k];
            pw[0] = pw3[0]; pw[1] = pw3[1]; pw[2] = pw3[2];
        }
        read6(c, a);
        rot6d(a, R);
        float tx, ty, tz; tvec(c, p, tx, ty, tz);
        chain_step(R, tx, ty, tz, Rw, pw);
        write3(c);
        if (c == 3) {
#pragma unroll
            for (int k = 0; k < 9; ++k) Rw3[k] = Rw[k];
            pw3[0] = pw[0]; pw3[1] = pw[1]; pw3[2] = pw[2];
        }
    }

    __syncthreads();
    // coalesced store of half A (out chunks 0..5; output floats live at slot dwords 0..23)
#pragma unroll
    for (int j = 0; j < 6; ++j) {
        int flat = 64 * j + lane;
        int le = flat / 6, lc = flat % 6;
        int ge = blockElem + le;
        const float* sp = (const float*)&W[le * SLOT];
        float4 v = *(const float4*)(sp + 4 * lc);
        if (ge < batch) out4[(size_t)ge * 12 + lc] = v;
    }
    __syncthreads();

    // ---- stage half B from prefetch registers ----
#pragma unroll
    for (int j = 0; j < 12; ++j) {
        int flat = 64 * j + lane;
        int le = flat / 12, lc = flat % 12;
        W[le * SLOT + lc] = vB[j];
    }
    __syncthreads();

    // ================= half B: joints 8..15 =================
    constexpr int PB[8] = {7, 8, 9, 3, 11, 12, 13, 14};   // parents of children 8..15
#pragma unroll
    for (int e = 0; e < 8; ++e) {
        const int c = e + 8, p = PB[e];
        if (p == 3) {   // restore branch state for joint 11
#pragma unroll
            for (int k = 0; k < 9; ++k) Rw[k] = Rw3[k];
            pw[0] = pw3[0]; pw[1] = pw3[1]; pw[2] = pw3[2];
        }
        read6(e, a);                 // local index e: input chunks restaged at 0..47
        rot6d(a, R);
        float tx, ty, tz; tvec(c, p, tx, ty, tz);
        chain_step(R, tx, ty, tz, Rw, pw);
        write3(e);
    }

    __syncthreads();
    // coalesced store of half B (out chunks 6..11)
#pragma unroll
    for (int j = 0; j < 6; ++j) {
        int flat = 64 * j + lane;
        int le = flat / 6, lc = flat % 6;
        int ge = blockElem + le;
        const float* sp = (const float*)&W[le * SLOT];
        float4 v = *(const float4*)(sp + 4 * lc);
        if (ge < batch) out4[(size_t)ge * 12 + 6 + lc] = v;
    }
}

} // namespace

extern "C" void kernel_launch(void* const* d_in, const int* in_sizes, int n_in,
                              void* d_out, int out_size, void* d_ws, size_t ws_size,
                              hipStream_t stream) {
    const float* angles = (const float*)d_in[0];   // [B, 16, 6] f32
    const float* xyz    = (const float*)d_in[1];   // [1, 16, 3] f32
    float* out          = (float*)d_out;           // [B, 16, 3] f32

    const int batch = in_sizes[0] / (NJ * 6);
    dim3 grid((batch + 63) / 64);
    skel_kernel<<<grid, 64, 0, stream>>>(angles, xyz, out, batch);
}